// Round 9
// baseline (390.320 us; speedup 1.0000x reference)
//
#include <hip/hip_runtime.h>
#include <stdint.h>

// Problem constants (LlamaAttention: B=2, S=2048, HID=2048, H=16, KH=4, D=128)
#define Bc   2
#define Sc   2048
#define HIDc 2048
#define Hc   16
#define KHc  4
#define Dc   128
#define HDc  2048   // H*D
#define KHDc 512    // KH*D
#define QKVS 3072   // fused QKV row stride (2048 Q + 512 K + 512 V)
#define SCALE2c 0.12751744657f       // D^-0.5 * log2(e)  (exp2 domain)
#define M0c 6.0f                     // fixed softmax shift (exp2 domain); see attn_v8
#define N_ITEMS2 768                 // pair-items: 512 split halves (p>=8) + 256 shorts

typedef _Float16 f16;
typedef _Float16 f16x2 __attribute__((ext_vector_type(2)));
typedef _Float16 f16x4 __attribute__((ext_vector_type(4)));
typedef _Float16 f16x8 __attribute__((ext_vector_type(8)));
typedef float    f32x4 __attribute__((ext_vector_type(4)));

// async global->LDS DMA, 16B per lane; LDS dest = (wave-uniform) base + lane*16
__device__ __forceinline__ void gl_lds16(const void* g, void* l) {
  __builtin_amdgcn_global_load_lds(
      (const __attribute__((address_space(1))) unsigned int*)g,
      (__attribute__((address_space(3))) unsigned int*)l, 16, 0, 0);
}

// ---------------------------------------------------------------- convert hs (x4 vec) + ctr init
__global__ __launch_bounds__(256) void conv_hs(const float* __restrict__ in,
                                               f16* __restrict__ out,
                                               int* __restrict__ ctr) {
  if (blockIdx.x == 0 && threadIdx.x == 0) *ctr = 0;
  int i = (blockIdx.x * 256 + threadIdx.x) * 4;
  float4 v = *(const float4*)&in[i];
  f16x4 o; o[0] = (f16)v.x; o[1] = (f16)v.y; o[2] = (f16)v.z; o[3] = (f16)v.w;
  *(f16x4*)&out[i] = o;
}

// ---------------------------------------------------------------- all weight transposes+convert
__global__ __launch_bounds__(256) void trw_all(const float* __restrict__ wq,
                                               const float* __restrict__ wk,
                                               const float* __restrict__ wv,
                                               const float* __restrict__ wo,
                                               f16* __restrict__ wqkvT,
                                               f16* __restrict__ woT) {
  const int z = blockIdx.z;
  const float* in; f16* out; int C, rowOff;
  if (z == 0)      { in = wq; out = wqkvT; C = 2048; rowOff = 0; }
  else if (z == 1) { in = wk; out = wqkvT; C = 512;  rowOff = 2048; }
  else if (z == 2) { in = wv; out = wqkvT; C = 512;  rowOff = 2560; }
  else             { in = wo; out = woT;   C = 2048; rowOff = 0; }
  if (blockIdx.x * 64 >= C) return;
  __shared__ float Ld[64 * 65];
  const int tid = threadIdx.x;
  const int r0 = blockIdx.y * 64, c0 = blockIdx.x * 64;
#pragma unroll
  for (int p = 0; p < 4; ++p) {
    int idx = p * 256 + tid;
    int r = idx >> 4, c4 = (idx & 15) * 4;
    float4 v = *(const float4*)&in[(size_t)(r0 + r) * C + c0 + c4];
    Ld[r * 65 + c4 + 0] = v.x; Ld[r * 65 + c4 + 1] = v.y;
    Ld[r * 65 + c4 + 2] = v.z; Ld[r * 65 + c4 + 3] = v.w;
  }
  __syncthreads();
#pragma unroll
  for (int p = 0; p < 4; ++p) {
    int idx = p * 256 + tid;
    int oc = idx >> 4, m4 = (idx & 15) * 4;
    f16x4 o;
#pragma unroll
    for (int i = 0; i < 4; ++i) o[i] = (f16)Ld[(m4 + i) * 65 + oc];
    *(f16x4*)&out[(size_t)(rowOff + c0 + oc) * 2048 + r0 + m4] = o;
  }
}

// ---------------------------------------------------------------- RoPE, f16x8 vectorized
__global__ __launch_bounds__(256) void rope8(f16* __restrict__ x,
                                             const float* __restrict__ cb,
                                             const float* __restrict__ sb) {
  int bid = blockIdx.x;
  int colbase, idx, h, row;
  if (bid < 2048) { idx = bid * 256 + threadIdx.x; colbase = 0;    h = (idx >> 3) & 15; row = idx >> 7; }
  else            { idx = (bid - 2048) * 256 + threadIdx.x; colbase = 2048; h = (idx >> 3) & 3;  row = idx >> 5; }
  const int d0 = (idx & 7) * 8;
  f16* p = x + (size_t)row * QKVS + colbase + h * 128 + d0;
  f16x8 x1 = *(const f16x8*)p;
  f16x8 x2 = *(const f16x8*)(p + 64);
  const float* cp = cb + (size_t)row * 128 + d0;
  const float* sp = sb + (size_t)row * 128 + d0;
  float4 c0 = *(const float4*)cp, c1 = *(const float4*)(cp + 4);
  float4 s0 = *(const float4*)sp, s1 = *(const float4*)(sp + 4);
  float cc[8] = {c0.x, c0.y, c0.z, c0.w, c1.x, c1.y, c1.z, c1.w};
  float ss[8] = {s0.x, s0.y, s0.z, s0.w, s1.x, s1.y, s1.z, s1.w};
  f16x8 y1, y2;
#pragma unroll
  for (int i = 0; i < 8; ++i) {
    float a = (float)x1[i], b = (float)x2[i];
    y1[i] = (f16)(a * cc[i] - b * ss[i]);
    y2[i] = (f16)(b * cc[i] + a * ss[i]);
  }
  *(f16x8*)p = y1;
  *(f16x8*)(p + 64) = y2;
}

// ---------------------------------------------------------------- V transpose
__global__ __launch_bounds__(256) void v_tr(const f16* __restrict__ QKV,
                                            f16* __restrict__ Vt) {
  __shared__ f16 Ld[64 * 78];
  const int tid = threadIdx.x;
  const int s0 = blockIdx.x * 64, d0 = blockIdx.y * 64;
  const int b = blockIdx.z >> 2, kh = blockIdx.z & 3;
#pragma unroll
  for (int p = 0; p < 2; ++p) {
    int idx = p * 256 + tid;
    int sl = idx >> 3, dc8 = (idx & 7) * 8;
    f16x8 v = *(const f16x8*)&QKV[(size_t)(b * Sc + s0 + sl) * QKVS + 2560 + kh * 128 + d0 + dc8];
#pragma unroll
    for (int i = 0; i < 4; ++i) {
      f16x2 w; w[0] = v[2 * i]; w[1] = v[2 * i + 1];
      *(f16x2*)&Ld[sl * 78 + dc8 + 2 * i] = w;
    }
  }
  __syncthreads();
  {
    int dr = (tid >> 3) * 2, sc8 = (tid & 7) * 8;
    f16x8 r0v, r1v;
#pragma unroll
    for (int j = 0; j < 8; ++j) {
      f16x2 w = *(const f16x2*)&Ld[(sc8 + j) * 78 + dr];
      r0v[j] = w[0]; r1v[j] = w[1];
    }
    size_t obase = ((size_t)(b * KHc + kh) * 128 + d0 + dr) * Sc + s0 + sc8;
    *(f16x8*)&Vt[obase]      = r0v;
    *(f16x8*)&Vt[obase + Sc] = r1v;
  }
}

// ---------------------------------------------------------------- pipelined GEMM v3: C = A @ Bt^T
// 256x(NREP*64) tile, 8 waves (2M x 4N), BK=64, double-buffered LDS,
// DEPTH-2 prefetch + counted vmcnt. Theory update (r8): TLP refuted —
// occupancy 21->40% with identical time/MfmaUtil(22%); the wall is the
// per-K-step drain stall (prefetch issued ~500cy before a vmcnt(0) wait vs
// ~900cy HBM latency; all waves in all resident blocks hit the same wait).
// Depth-2 gives DMAs ~2 compute phases of flight; vmcnt(7|6) drains only
// tile-t's own loads, never 0 mid-loop (m218: counted vs drain0 +38-73%).
// Schedule per tile t:
//   vmcnt(L) [L=loads/tile: 7 A+B for NREP=3, 6 for NREP=2]; barrier;
//   22 ds_read + 48 MFMA; barrier; stage(t+2 -> buf[cur]).
// Correctness: per-wave FIFO — at top of t, outstanding = t's L + t+1's L;
// vmcnt(L) drains t's. Barrier then publishes ALL waves' granules. End
// barrier retires every wave's reads of buf[cur] before restage (WAR);
// sched_barrier(0) fences stop the compiler hoisting stage across it.
// The asm idiom (counted vmcnt + raw s_barrier, depth-2) is harness-proven
// in attn_v8 (round 7). Grids = exactly 256 blocks (1/CU; no cross-block
// TLP exists at 112KB LDS, which is WHY the explicit pipeline is needed).
template<int NREP, int CF16>
__global__ __launch_bounds__(512, 2) void gemm8p2(const f16* __restrict__ A,
                                                  const f16* __restrict__ Bt,
                                                  void* __restrict__ Cout,
                                                  int K, int cstride) {
  __shared__ f16 Al[2][16384];           // 256 rows x 64 k per buffer (32 KB)
  __shared__ f16 Bl[2][NREP * 4096];     // NREP*64 rows x 64 k per buffer
  const int tid  = threadIdx.x;
  const int lane = tid & 63, wave = tid >> 6;     // 8 waves
  const int quad = lane >> 4, l16 = lane & 15;
  const int wm = wave >> 2, wn = wave & 3;        // 2 (M) x 4 (N) wave grid
  const int m0 = blockIdx.y * 256, n0 = blockIdx.x * (NREP * 64);
  f32x4 acc[8][NREP] = {};

  // A: 32 granules/tile (4 per wave); B: 8*NREP granules (NREP per wave).
  // Granule = 16 rows x 32 k staged as 64 lanes x 16B; layout matches the
  // fragment-read index (proven, 0 bank conflicts).
  auto stage = [&](int buf, int k0) {
#pragma unroll
    for (int p = 0; p < 4; ++p) {
      const int g  = wave * 2 + (p >> 1);
      const int kq = (p & 1) * 4 + quad;
      gl_lds16(&A[(size_t)(m0 + g * 16 + l16) * K + k0 + kq * 8],
               &Al[buf][(wave * 4 + p) * 512]);
    }
#pragma unroll
    for (int p = 0; p < NREP; ++p) {
      const int gb = wave * NREP + p;
      const int gi = gb >> 1, kh2 = gb & 1;
      gl_lds16(&Bt[(size_t)(n0 + gi * 16 + l16) * K + k0 + kh2 * 32 + quad * 8],
               &Bl[buf][gb * 512]);
    }
  };

  const int NT = K >> 6;
  stage(0, 0);
  stage(1, 64);          // NT >= 2 always here (K >= 128)
  for (int t = 0; t < NT; ++t) {
    const int cur = t & 1;
    // counted wait: drain own tile-t loads (oldest L), keep t+1's in flight
    if (t + 1 < NT) {
      if constexpr (NREP == 3) { asm volatile("s_waitcnt vmcnt(7)" ::: "memory"); }
      else                     { asm volatile("s_waitcnt vmcnt(6)" ::: "memory"); }
    } else {
      asm volatile("s_waitcnt vmcnt(0)" ::: "memory");
    }
    __builtin_amdgcn_sched_barrier(0);
    __builtin_amdgcn_s_barrier();       // all waves: buf[cur] fully landed
    __builtin_amdgcn_sched_barrier(0);

    f16x8 bf[NREP][2];
#pragma unroll
    for (int j = 0; j < NREP; ++j)
#pragma unroll
      for (int ks = 0; ks < 2; ++ks)
        bf[j][ks] = *(const f16x8*)&Bl[cur][(((wn * NREP + j) * 8 + ks * 4 + quad) * 16 + l16) * 8];
#pragma unroll
    for (int mh = 0; mh < 2; ++mh) {
      f16x8 af[4][2];
#pragma unroll
      for (int i = 0; i < 4; ++i)
#pragma unroll
        for (int ks = 0; ks < 2; ++ks)
          af[i][ks] = *(const f16x8*)&Al[cur][(((wm * 8 + mh * 4 + i) * 8 + ks * 4 + quad) * 16 + l16) * 8];
      __builtin_amdgcn_s_setprio(1);
#pragma unroll
      for (int ks = 0; ks < 2; ++ks)
#pragma unroll
        for (int i = 0; i < 4; ++i)
#pragma unroll
          for (int j = 0; j < NREP; ++j)
            acc[mh * 4 + i][j] = __builtin_amdgcn_mfma_f32_16x16x32_f16(
                af[i][ks], bf[j][ks], acc[mh * 4 + i][j], 0, 0, 0);
      __builtin_amdgcn_s_setprio(0);
    }

    // end barrier: all waves' reads of buf[cur] retired -> WAR-safe to restage
    __builtin_amdgcn_sched_barrier(0);
    __builtin_amdgcn_s_barrier();
    __builtin_amdgcn_sched_barrier(0);
    if (t + 2 < NT) stage(cur, (t + 2) * 64);   // tile t+2 uses buf[cur]
  }

  const int rbase = m0 + wm * 128;
  const int cbase = n0 + wn * NREP * 16;
#pragma unroll
  for (int mi = 0; mi < 8; ++mi)
#pragma unroll
    for (int j = 0; j < NREP; ++j)
#pragma unroll
      for (int r = 0; r < 4; ++r) {
        size_t idx = (size_t)(rbase + mi * 16 + quad * 4 + r) * cstride + cbase + j * 16 + l16;
        if (CF16) ((f16*)Cout)[idx]   = (f16)acc[mi][j][r];
        else      ((float*)Cout)[idx] = acc[mi][j][r];
      }
}

// ---------------------------------------------------------------- fused causal attention v8
// KNOWN-GOOD (round 7/8: ~90us, passed twice). Unchanged.
__global__ __launch_bounds__(512, 4) void attn_v8(const f16* __restrict__ QKV,
                                                  const f16* __restrict__ Vt,
                                                  f16* __restrict__ Ob,
                                                  f16* __restrict__ Opart,
                                                  float2* __restrict__ ML,
                                                  int* __restrict__ ctr) {
  __shared__ f16 Kl[2][8192];
  __shared__ f16 Vl[2][8192];
  __shared__ f16 Ps[8 * 512];    // per-wave 16x32 P tile: w*512+(col>>3)*128+row*8+(col&7)
  __shared__ int item_s;
  const int tid  = threadIdx.x;
  const int lane = tid & 63, wave = tid >> 6;   // 0..7
  const int quad = lane >> 4, l16 = lane & 15;
  const int qsel = wave >> 2, wv = wave & 3;    // q-tile select, row-group

  // ones B-fragment: col 0 = 1 -> MFMA accumulates P row-sums into C col 0
  f16x8 ones_f;
#pragma unroll
  for (int i = 0; i < 8; ++i) ones_f[i] = (l16 == 0) ? (f16)1.0f : (f16)0.0f;

  for (;;) {
    if (tid == 0) item_s = atomicAdd(ctr, 1);
    __syncthreads();
    const int item = item_s;
    if (item >= N_ITEMS2) break;

    // ---- cost-descending pair-item map. Bands c=16..9: halves of pair
    // p=c-1 (64 items) plus, when c even, shorts of pair p=c/2-1 (32 items).
    // Tail: shorts p=3..0.
    int p, bh, k0t, k1t, hf = -1;
    if (item < 640) {
      int base = 0, c = 16;
#pragma unroll 1
      for (; c >= 9; --c) {
        int sz = (c & 1) ? 64 : 96;
        if (item < base + sz) break;
        base += sz;
      }
      int off = item - base;
      if (off < 64) {
        p = c - 1; hf = off >> 5; bh = off & 31;
        int hn = p + 1;                       // half point of nk=2p+2
        k0t = hf ? hn : 0; k1t = hf ? 2 * p + 2 : hn;
      } else {
        p = (c >> 1) - 1; bh = off - 64; k0t = 0; k1t = 2 * p + 2;
      }
    } else {
      int off = item - 640;
      p = 3 - (off >> 5); bh = off & 31; k0t = 0; k1t = 2 * p + 2;
    }
    const int b = bh >> 4, h = bh & 15, kh = h >> 2;
    const int qt = 2 * p + qsel;              // this wave's q-tile
    const int qbase = qt * 64 + wv * 16;      // this wave's 16 q-rows

    f16x8 qf[4];
    {
      const f16* qp = QKV + (size_t)(b * Sc + qbase + l16) * QKVS + h * 128 + quad * 8;
#pragma unroll
      for (int c = 0; c < 4; ++c) qf[c] = *(const f16x8*)(qp + c * 32);
    }
    f32x4 ls = {};
    f32x4 o[8] = {};

    // 8-wave staging split: K granule g (g>>2 = row-group, g&3 = k-chunk),
    // V granule g (g>>1 = d-group, g&1 = s-chunk); wave stages g = wave*2+{0,1}.
    auto stageKV = [&](int kt, int buf) {
#pragma unroll
      for (int p2 = 0; p2 < 2; ++p2) {
        const int g = wave * 2 + p2;
        gl_lds16(&QKV[(size_t)(b * Sc + kt * 64 + (g >> 2) * 16 + l16) * QKVS + 2048 + kh * 128 + (g & 3) * 32 + quad * 8],
                 &Kl[buf][g * 512]);
      }
#pragma unroll
      for (int p2 = 0; p2 < 2; ++p2) {
        const int g = wave * 2 + p2;
        gl_lds16(&Vt[(size_t)((b * KHc + kh) * 128 + (g >> 1) * 16 + l16) * Sc + kt * 64 + (g & 1) * 32 + quad * 8],
                 &Vl[buf][g * 512]);
      }
    };

    stageKV(k0t, 0);                          // depth-2 prologue
    stageKV(k0t + 1, 1);                      // k1t-k0t >= 2 for every item

    for (int kt = k0t; kt < k1t; ++kt) {
      const int cur = (kt - k0t) & 1;
      // counted wait: drain own tile-kt DMAs, keep kt+1's 4 in flight
      if (kt + 1 < k1t) { asm volatile("s_waitcnt vmcnt(4)" ::: "memory"); }
      else              { asm volatile("s_waitcnt vmcnt(0)" ::: "memory"); }
      __builtin_amdgcn_sched_barrier(0);
      __builtin_amdgcn_s_barrier();           // all granules for tile kt landed
      __builtin_amdgcn_sched_barrier(0);

      if (kt <= qt) {                         // wave-uniform causal skip
        // ---- scores for all 4 16-col groups
        __builtin_amdgcn_s_setprio(1);
        f32x4 s4[4] = {};
#pragma unroll
        for (int kc = 0; kc < 2; ++kc)
#pragma unroll
          for (int c = 0; c < 4; ++c) {
            f16x8 ka = *(const f16x8*)&Kl[cur][(((kc * 2 + 0) * 4 + c) * 4 + quad) * 128 + l16 * 8];
            f16x8 kb = *(const f16x8*)&Kl[cur][(((kc * 2 + 1) * 4 + c) * 4 + quad) * 128 + l16 * 8];
            s4[kc * 2 + 0] = __builtin_amdgcn_mfma_f32_16x16x32_f16(qf[c], ka, s4[kc * 2 + 0], 0, 0, 0);
            s4[kc * 2 + 1] = __builtin_amdgcn_mfma_f32_16x16x32_f16(qf[c], kb, s4[kc * 2 + 1], 0, 0, 0);
          }
        __builtin_amdgcn_s_setprio(0);

        // ---- softmax, fixed shift M0c (exp2 domain); mask only on diag tile
        const bool diag = (kt == qt);
        const int cb = kt * 64 + l16;
        const int wb  = wave * 512 + (l16 & 7);
        const int rhi = l16 >> 3;
        float e2[4], e3[4];
#pragma unroll
        for (int r = 0; r < 4; ++r) {
          float v0 = fmaf(s4[0][r], SCALE2c, -M0c);
          float v1 = fmaf(s4[1][r], SCALE2c, -M0c);
          float v2 = fmaf(s4[2][r], SCALE2c, -M0c);
          float v3 = fmaf(s4[3][r], SCALE2c, -M0c);
          if (diag) {
            const int qrow = qbase + quad * 4 + r;
            if (cb      > qrow) v0 = -1e30f;
            if (cb + 16 > qrow) v1 = -1e30f;
            if (cb + 32 > qrow) v2 = -1e30f;
            if (cb + 48 > qrow) v3 = -1e30f;
          }
          float p0 = exp2f(v0), p1 = exp2f(v1);
          e2[r] = exp2f(v2); e3[r] = exp2f(v3);
          const int rowoff = (quad * 4 + r) * 8;
          Ps[wb + (rhi + 0) * 128 + rowoff] = (f16)p0;
          Ps[wb + (rhi + 2) * 128 + rowoff] = (f16)p1;
        }

        // ---- PV chunk kc=0 (cols 0..31) + row-sum MFMA (Ps wave-local)
        {
          f16x8 pf = *(const f16x8*)&Ps[wave * 512 + quad * 128 + l16 * 8];
          __builtin_amdgcn_s_setprio(1);
          ls = __builtin_amdgcn_mfma_f32_16x16x32_f16(pf, ones_f, ls, 0, 0, 0);
#pragma unroll
          for (int dt = 0; dt < 8; ++dt) {
            f16x8 vf = *(const f16x8*)&Vl[cur][((dt * 2 + 0) * 4 + quad) * 128 + l16 * 8];
            o[dt] = __builtin_amdgcn_mfma_f32_16x16x32_f16(pf, vf, o[dt], 0, 0, 0);
          }
          __builtin_amdgcn_s_setprio(0);
        }
        // ---- PV chunk kc=1 (cols 32..63); wave-local DS in-order -> WAR-safe
#pragma unroll
        for (int r = 0; r < 4; ++r) {
          const int rowoff = (quad * 4 + r) * 8;
          Ps[wb + (rhi + 0) * 128 + rowoff] = (f16)e2[r];
          Ps[wb + (rhi + 2) * 128 + rowoff] = (f16)e3[r];
        }
        {
          f16x8 pf = *(const f16x8*)&Ps[wave * 512 + quad * 128 + l16 * 8];
          __builtin_amdgcn_s_setprio(1);
          ls = __builtin_amdgcn_mfma_f32_16x16x32_f16(pf, ones_f, ls, 0, 0, 0);
#pragma unroll
          for (int dt = 0; dt < 8; ++dt) {
            f16x8 vf = *(const f16x8*)&Vl[cur][((dt * 2 + 1) * 4 + quad) * 128 + l16 * 8];
            o[dt] = __builtin_amdgcn_mfma_f32_16x16x32_f16(pf, vf, o[dt], 0, 0, 0);
          }
          __builtin_amdgcn_s_setprio(0);
        }
      }

      // end barrier: all waves' reads of buf[cur] retired -> WAR-safe restage
      __builtin_amdgcn_sched_barrier(0);
      __builtin_amdgcn_s_barrier();
      __builtin_amdgcn_sched_barrier(0);
      if (kt + 2 < k1t) stageKV(kt + 2, cur);   // tile kt+2 uses buf[cur]
    }

    // ---- epilogue: l lives in lanes l16==0 (C col 0); broadcast within quad
    float inv[4], lrow[4];
#pragma unroll
    for (int r = 0; r < 4; ++r) {
      lrow[r] = __shfl(ls[r], lane & 48);
      inv[r] = 1.0f / lrow[r];
    }
    const int rl = wv * 16 + quad * 4;
    if (hf < 0) {
#pragma unroll
      for (int dt = 0; dt < 8; ++dt)
#pragma unroll
        for (int r = 0; r < 4; ++r)
          Ob[(size_t)(b * Sc + qbase + quad * 4 + r) * HDc + h * 128 + dt * 16 + l16] =
              (f16)(o[dt][r] * inv[r]);
    } else {
      const int tile = (qt - 16) * 32 + bh;   // qt = 2p+qsel in 16..31 for p>=8
      f16* op = Opart + ((size_t)tile * 2 + hf) * (64 * 128);
#pragma unroll
      for (int dt = 0; dt < 8; ++dt)
#pragma unroll
        for (int r = 0; r < 4; ++r)
          op[(rl + r) * 128 + dt * 16 + l16] = (f16)(o[dt][r] * inv[r]);
      if (l16 == 0) {
#pragma unroll
        for (int r = 0; r < 4; ++r) {
          float2 ml; ml.x = M0c; ml.y = lrow[r];
          ML[((size_t)tile * 2 + hf) * 64 + rl + r] = ml;
        }
      }
    }
  }
}

// ---------------------------------------------------------------- merge split-K halves
__global__ __launch_bounds__(256) void attn_merge(const f16* __restrict__ Opart,
                                                  const float2* __restrict__ ML,
                                                  f16* __restrict__ Ob) {
  const int tile = blockIdx.x;
  const int qt = 16 + (tile >> 5), bh = tile & 31;
  const int b = bh >> 4, h = bh & 15;
  const int tid = threadIdx.x;
  const int row = tid >> 2, c0 = (tid & 3) * 32;
  float2 ml1 = ML[(size_t)tile * 2 * 64 + row];
  float2 ml2 = ML[((size_t)tile * 2 + 1) * 64 + row];
  float m = fmaxf(ml1.x, ml2.x);
  float w1 = ml1.y * exp2f(ml1.x - m);
  float w2 = ml2.y * exp2f(ml2.x - m);
  float rinv = 1.0f / (w1 + w2);
  float a1 = w1 * rinv, a2 = w2 * rinv;
  const f16* o1 = Opart + (size_t)tile * 2 * (64 * 128) + row * 128 + c0;
  const f16* o2 = o1 + 64 * 128;
  f16* out = Ob + (size_t)(b * Sc + qt * 64 + row) * HDc + h * 128 + c0;
#pragma unroll
  for (int j = 0; j < 4; ++j) {
    f16x8 x1 = *(const f16x8*)(o1 + j * 8);
    f16x8 x2 = *(const f16x8*)(o2 + j * 8);
    f16x8 y;
#pragma unroll
    for (int i = 0; i < 8; ++i) y[i] = (f16)(a1 * (float)x1[i] + a2 * (float)x2[i]);
    *(f16x8*)(out + j * 8) = y;
  }
}

// ---------------------------------------------------------------- launch
extern "C" void kernel_launch(void* const* d_in, const int* in_sizes, int n_in,
                              void* d_out, int out_size, void* d_ws, size_t ws_size,
                              hipStream_t stream) {
  (void)in_sizes; (void)n_in; (void)out_size; (void)ws_size;
  const float* hs   = (const float*)d_in[0];
  const float* cosb = (const float*)d_in[1];
  const float* sinb = (const float*)d_in[2];
  // d_in[3] = attention_mask: pure causal, in-kernel.
  const float* wq = (const float*)d_in[4];
  const float* wk = (const float*)d_in[5];
  const float* wv = (const float*)d_in[6];
  const float* wo = (const float*)d_in[7];
  float* out = (float*)d_out;

  char* ws = (char*)d_ws;
  int*  ctr = (int*)ws;
  size_t off = 256;
  auto alloc = [&](size_t bytes) { char* p = ws + off; off += (bytes + 255) & ~(size_t)255; return p; };
  f16*  hsF   = (f16*)alloc((size_t)Bc * Sc * HIDc * 2);      // 16.8 MB (reused as attn out)
  f16*  woT   = (f16*)alloc((size_t)HIDc * HDc * 2);          //  8.4 MB
  f16*  QKVf  = (f16*)alloc((size_t)Bc * Sc * QKVS * 2);      // 25.2 MB
  f16*  Vt_g  = (f16*)alloc((size_t)Bc * KHc * Dc * Sc * 2);  //  4.2 MB
  f16*  wqkvT = (f16*)alloc((size_t)QKVS * HIDc * 2);         // 12.6 MB (dead after QKV GEMM)
  // Opart aliases wqkvT (16.8 MB needs 12.6 + 4.2 fresh tail)
  f16*  Opart = wqkvT;
  {
    size_t opart_bytes = (size_t)512 * 2 * 64 * 128 * 2;      // 16.8 MB
    size_t wqkvT_bytes = (size_t)QKVS * HIDc * 2;
    if (opart_bytes > wqkvT_bytes) off += opart_bytes - wqkvT_bytes;
  }
  float2* ML = (float2*)alloc((size_t)512 * 2 * 64 * sizeof(float2));  // 0.5 MB
  f16*  attnF = hsF;   // hsF dead after QKV GEMM

  conv_hs<<<8192, 256, 0, stream>>>(hs, hsF, ctr);
  trw_all<<<dim3(32, 32, 4), 256, 0, stream>>>(wq, wk, wv, wo, wqkvT, woT);

  // QKV GEMM: C(4096,3072) f16 stride QKVS; 256x192 tiles -> grid 16x16 = 256 blocks (1/CU)
  gemm8p2<3, 1><<<dim3(16, 16), 512, 0, stream>>>(hsF, wqkvT, QKVf, 2048, QKVS);

  rope8<<<2560, 256, 0, stream>>>(QKVf, cosb, sinb);
  v_tr<<<dim3(32, 2, 8), 256, 0, stream>>>(QKVf, Vt_g);

  attn_v8<<<512, 512, 0, stream>>>(QKVf, Vt_g, attnF, Opart, ML, ctr);
  attn_merge<<<512, 256, 0, stream>>>(Opart, ML, attnF);

  // out-proj GEMM: C(4096,2048) f32; 256x128 tiles -> grid 16x16 = 256 blocks (1/CU)
  gemm8p2<2, 0><<<dim3(16, 16), 512, 0, stream>>>(attnF, woT, out, 2048, 2048);
}

// Round 12
// 380.002 us; speedup vs baseline: 1.0272x; 1.0272x over previous
//
#include <hip/hip_runtime.h>
#include <stdint.h>

// Problem constants (LlamaAttention: B=2, S=2048, HID=2048, H=16, KH=4, D=128)
#define Bc   2
#define Sc   2048
#define HIDc 2048
#define Hc   16
#define KHc  4
#define Dc   128
#define HDc  2048   // H*D
#define KHDc 512    // KH*D
#define QKVS 3072   // fused QKV row stride (2048 Q + 512 K + 512 V)
#define SCALE2c 0.12751744657f       // D^-0.5 * log2(e)  (exp2 domain)
#define M0c 6.0f                     // fixed softmax shift (exp2 domain); see attn_v8
#define N_ITEMS2 768                 // pair-items: 512 split halves (p>=8) + 256 shorts

typedef _Float16 f16;
typedef _Float16 f16x2 __attribute__((ext_vector_type(2)));
typedef _Float16 f16x4 __attribute__((ext_vector_type(4)));
typedef _Float16 f16x8 __attribute__((ext_vector_type(8)));
typedef float    f32x4 __attribute__((ext_vector_type(4)));

// async global->LDS DMA, 16B per lane; LDS dest = (wave-uniform) base + lane*16
__device__ __forceinline__ void gl_lds16(const void* g, void* l) {
  __builtin_amdgcn_global_load_lds(
      (const __attribute__((address_space(1))) unsigned int*)g,
      (__attribute__((address_space(3))) unsigned int*)l, 16, 0, 0);
}

// ---------------------------------------------------------------- convert hs (x4 vec) + ctr init
__global__ __launch_bounds__(256) void conv_hs(const float* __restrict__ in,
                                               f16* __restrict__ out,
                                               int* __restrict__ ctr) {
  if (blockIdx.x == 0 && threadIdx.x == 0) *ctr = 0;
  int i = (blockIdx.x * 256 + threadIdx.x) * 4;
  float4 v = *(const float4*)&in[i];
  f16x4 o; o[0] = (f16)v.x; o[1] = (f16)v.y; o[2] = (f16)v.z; o[3] = (f16)v.w;
  *(f16x4*)&out[i] = o;
}

// ---------------------------------------------------------------- all weight transposes+convert
__global__ __launch_bounds__(256) void trw_all(const float* __restrict__ wq,
                                               const float* __restrict__ wk,
                                               const float* __restrict__ wv,
                                               const float* __restrict__ wo,
                                               f16* __restrict__ wqkvT,
                                               f16* __restrict__ woT) {
  const int z = blockIdx.z;
  const float* in; f16* out; int C, rowOff;
  if (z == 0)      { in = wq; out = wqkvT; C = 2048; rowOff = 0; }
  else if (z == 1) { in = wk; out = wqkvT; C = 512;  rowOff = 2048; }
  else if (z == 2) { in = wv; out = wqkvT; C = 512;  rowOff = 2560; }
  else             { in = wo; out = woT;   C = 2048; rowOff = 0; }
  if (blockIdx.x * 64 >= C) return;
  __shared__ float Ld[64 * 65];
  const int tid = threadIdx.x;
  const int r0 = blockIdx.y * 64, c0 = blockIdx.x * 64;
#pragma unroll
  for (int p = 0; p < 4; ++p) {
    int idx = p * 256 + tid;
    int r = idx >> 4, c4 = (idx & 15) * 4;
    float4 v = *(const float4*)&in[(size_t)(r0 + r) * C + c0 + c4];
    Ld[r * 65 + c4 + 0] = v.x; Ld[r * 65 + c4 + 1] = v.y;
    Ld[r * 65 + c4 + 2] = v.z; Ld[r * 65 + c4 + 3] = v.w;
  }
  __syncthreads();
#pragma unroll
  for (int p = 0; p < 4; ++p) {
    int idx = p * 256 + tid;
    int oc = idx >> 4, m4 = (idx & 15) * 4;
    f16x4 o;
#pragma unroll
    for (int i = 0; i < 4; ++i) o[i] = (f16)Ld[(m4 + i) * 65 + oc];
    *(f16x4*)&out[(size_t)(rowOff + c0 + oc) * 2048 + r0 + m4] = o;
  }
}

// ---------------------------------------------------------------- RoPE, f16x8 vectorized
__global__ __launch_bounds__(256) void rope8(f16* __restrict__ x,
                                             const float* __restrict__ cb,
                                             const float* __restrict__ sb) {
  int bid = blockIdx.x;
  int colbase, idx, h, row;
  if (bid < 2048) { idx = bid * 256 + threadIdx.x; colbase = 0;    h = (idx >> 3) & 15; row = idx >> 7; }
  else            { idx = (bid - 2048) * 256 + threadIdx.x; colbase = 2048; h = (idx >> 3) & 3;  row = idx >> 5; }
  const int d0 = (idx & 7) * 8;
  f16* p = x + (size_t)row * QKVS + colbase + h * 128 + d0;
  f16x8 x1 = *(const f16x8*)p;
  f16x8 x2 = *(const f16x8*)(p + 64);
  const float* cp = cb + (size_t)row * 128 + d0;
  const float* sp = sb + (size_t)row * 128 + d0;
  float4 c0 = *(const float4*)cp, c1 = *(const float4*)(cp + 4);
  float4 s0 = *(const float4*)sp, s1 = *(const float4*)(sp + 4);
  float cc[8] = {c0.x, c0.y, c0.z, c0.w, c1.x, c1.y, c1.z, c1.w};
  float ss[8] = {s0.x, s0.y, s0.z, s0.w, s1.x, s1.y, s1.z, s1.w};
  f16x8 y1, y2;
#pragma unroll
  for (int i = 0; i < 8; ++i) {
    float a = (float)x1[i], b = (float)x2[i];
    y1[i] = (f16)(a * cc[i] - b * ss[i]);
    y2[i] = (f16)(b * cc[i] + a * ss[i]);
  }
  *(f16x8*)p = y1;
  *(f16x8*)(p + 64) = y2;
}

// ---------------------------------------------------------------- V transpose
__global__ __launch_bounds__(256) void v_tr(const f16* __restrict__ QKV,
                                            f16* __restrict__ Vt) {
  __shared__ f16 Ld[64 * 78];
  const int tid = threadIdx.x;
  const int s0 = blockIdx.x * 64, d0 = blockIdx.y * 64;
  const int b = blockIdx.z >> 2, kh = blockIdx.z & 3;
#pragma unroll
  for (int p = 0; p < 2; ++p) {
    int idx = p * 256 + tid;
    int sl = idx >> 3, dc8 = (idx & 7) * 8;
    f16x8 v = *(const f16x8*)&QKV[(size_t)(b * Sc + s0 + sl) * QKVS + 2560 + kh * 128 + d0 + dc8];
#pragma unroll
    for (int i = 0; i < 4; ++i) {
      f16x2 w; w[0] = v[2 * i]; w[1] = v[2 * i + 1];
      *(f16x2*)&Ld[sl * 78 + dc8 + 2 * i] = w;
    }
  }
  __syncthreads();
  {
    int dr = (tid >> 3) * 2, sc8 = (tid & 7) * 8;
    f16x8 r0v, r1v;
#pragma unroll
    for (int j = 0; j < 8; ++j) {
      f16x2 w = *(const f16x2*)&Ld[(sc8 + j) * 78 + dr];
      r0v[j] = w[0]; r1v[j] = w[1];
    }
    size_t obase = ((size_t)(b * KHc + kh) * 128 + d0 + dr) * Sc + s0 + sc8;
    *(f16x8*)&Vt[obase]      = r0v;
    *(f16x8*)&Vt[obase + Sc] = r1v;
  }
}

// ---------------------------------------------------------------- 4-phase GEMM: C = A @ Bt^T
// 256x(NREP*64) tile, 8 waves (2M x 4N), BK=64, double-buffered LDS.
// Identical to round-10's FIXED version (mm called with row-half 0,1,0,1;
// K-halves accumulate into the same acc — guide's K-loop accumulator
// recipe). Round-10's buggy variant RAN to completion (no hang) and this
// fix only changes accumulator indexing, so the round-11 container failure
// is attributed to infra (cf. round 6 fail -> round 7 pass, same source).
// Audit (3x): granule store 2R+kh <-> read R*1024+ks*512 bijection; RAW via
// tile-top vmcnt(0)+barrier; WAR via per-wave lgkmcnt(0) fences + top
// barrier before restage; rule-#18 sched_barrier fencing; uniform barriers.
// Rationale (r9): depth/occupancy/counted-vmcnt all null at ~22% MfmaUtil;
// m196/m201: the lever is the fine ds_read||stage||MFMA phase interleave.
template<int NREP, int CF16>
__global__ __launch_bounds__(512, 2) void gemm4p(const f16* __restrict__ A,
                                                 const f16* __restrict__ Bt,
                                                 void* __restrict__ Cout,
                                                 int K, int cstride) {
  __shared__ f16 Al[2][16384];           // 256 rows x 64 k per buffer (32 KB)
  __shared__ f16 Bl[2][NREP * 4096];     // NREP*64 rows x 64 k per buffer
  const int tid  = threadIdx.x;
  const int lane = tid & 63, wave = tid >> 6;     // 8 waves
  const int quad = lane >> 4, l16 = lane & 15;
  const int wm = wave >> 2, wn = wave & 3;        // 2 (M) x 4 (N) wave grid
  const int m0 = blockIdx.y * 256, n0 = blockIdx.x * (NREP * 64);
  f32x4 acc[8][NREP] = {};

  auto stageA = [&](int buf, int k0, int p) {    // p in 0..3
    const int g  = wave * 2 + (p >> 1);
    const int kq = (p & 1) * 4 + quad;
    gl_lds16(&A[(size_t)(m0 + g * 16 + l16) * K + k0 + kq * 8],
             &Al[buf][(wave * 4 + p) * 512]);
  };
  auto stageB = [&](int buf, int k0, int p) {    // p in 0..NREP-1
    const int gb = wave * NREP + p;
    const int gi = gb >> 1, kh2 = gb & 1;
    gl_lds16(&Bt[(size_t)(n0 + gi * 16 + l16) * K + k0 + kh2 * 32 + quad * 8],
             &Bl[buf][gb * 512]);
  };

  const int NT = K >> 6;
  // prologue: stage tile 0 fully
#pragma unroll
  for (int p = 0; p < 4; ++p) stageA(0, 0, p);
#pragma unroll
  for (int p = 0; p < NREP; ++p) stageB(0, 0, p);

  for (int t = 0; t < NT; ++t) {
    const int cur = t & 1;
    const bool pf = (t + 1 < NT);
    const int nk0 = (t + 1) * 64;

    // tile top: tile-t granules landed; all reads of buf^1 retired (WAR)
    asm volatile("s_waitcnt vmcnt(0)" ::: "memory");
    __builtin_amdgcn_sched_barrier(0);
    __builtin_amdgcn_s_barrier();
    __builtin_amdgcn_sched_barrier(0);

    f16x8 af[4], bf[NREP];
    auto rdA = [&](int mh, int ks) {
#pragma unroll
      for (int i = 0; i < 4; ++i)
        af[i] = *(const f16x8*)&Al[cur][(((wm * 8 + mh * 4 + i) * 8 + ks * 4 + quad) * 16 + l16) * 8];
    };
    auto rdB = [&](int ks) {
#pragma unroll
      for (int j = 0; j < NREP; ++j)
        bf[j] = *(const f16x8*)&Bl[cur][(((wn * NREP + j) * 8 + ks * 4 + quad) * 16 + l16) * 8];
    };
    auto fence = [&]() {
      __builtin_amdgcn_sched_barrier(0);
      __builtin_amdgcn_s_barrier();
      __builtin_amdgcn_sched_barrier(0);
      asm volatile("s_waitcnt lgkmcnt(0)" ::: "memory");
      __builtin_amdgcn_sched_barrier(0);
    };
    auto mm = [&](int mh) {                      // mh = row-half, 0 or 1
      __builtin_amdgcn_s_setprio(1);
#pragma unroll
      for (int i = 0; i < 4; ++i)
#pragma unroll
        for (int j = 0; j < NREP; ++j)
          acc[mh * 4 + i][j] = __builtin_amdgcn_mfma_f32_16x16x32_f16(
              af[i], bf[j], acc[mh * 4 + i][j], 0, 0, 0);
      __builtin_amdgcn_s_setprio(0);
    };

    // P0: (mh0, ks0)
    rdA(0, 0); rdB(0);
    if (pf) { stageA(cur ^ 1, nk0, 0); stageA(cur ^ 1, nk0, 1); stageB(cur ^ 1, nk0, 0); }
    fence(); mm(0);
    // P1: (mh1, ks0) — bf(ks0) still live
    rdA(1, 0);
    if (pf) { stageA(cur ^ 1, nk0, 2); stageA(cur ^ 1, nk0, 3); }
    fence(); mm(1);
    // P2: (mh0, ks1)
    rdA(0, 1); rdB(1);
    if (pf) {
#pragma unroll
      for (int j = 1; j < NREP; ++j) stageB(cur ^ 1, nk0, j);
    }
    fence(); mm(0);
    // P3: (mh1, ks1)
    rdA(1, 1);
    fence(); mm(1);
  }

  const int rbase = m0 + wm * 128;
  const int cbase = n0 + wn * NREP * 16;
#pragma unroll
  for (int mi = 0; mi < 8; ++mi)
#pragma unroll
    for (int j = 0; j < NREP; ++j)
#pragma unroll
      for (int r = 0; r < 4; ++r) {
        size_t idx = (size_t)(rbase + mi * 16 + quad * 4 + r) * cstride + cbase + j * 16 + l16;
        if (CF16) ((f16*)Cout)[idx]   = (f16)acc[mi][j][r];
        else      ((float*)Cout)[idx] = acc[mi][j][r];
      }
}

// ---------------------------------------------------------------- fused causal attention v8
// KNOWN-GOOD (rounds 7-9: ~90us, passed three times). Unchanged.
__global__ __launch_bounds__(512, 4) void attn_v8(const f16* __restrict__ QKV,
                                                  const f16* __restrict__ Vt,
                                                  f16* __restrict__ Ob,
                                                  f16* __restrict__ Opart,
                                                  float2* __restrict__ ML,
                                                  int* __restrict__ ctr) {
  __shared__ f16 Kl[2][8192];
  __shared__ f16 Vl[2][8192];
  __shared__ f16 Ps[8 * 512];    // per-wave 16x32 P tile: w*512+(col>>3)*128+row*8+(col&7)
  __shared__ int item_s;
  const int tid  = threadIdx.x;
  const int lane = tid & 63, wave = tid >> 6;   // 0..7
  const int quad = lane >> 4, l16 = lane & 15;
  const int qsel = wave >> 2, wv = wave & 3;    // q-tile select, row-group

  // ones B-fragment: col 0 = 1 -> MFMA accumulates P row-sums into C col 0
  f16x8 ones_f;
#pragma unroll
  for (int i = 0; i < 8; ++i) ones_f[i] = (l16 == 0) ? (f16)1.0f : (f16)0.0f;

  for (;;) {
    if (tid == 0) item_s = atomicAdd(ctr, 1);
    __syncthreads();
    const int item = item_s;
    if (item >= N_ITEMS2) break;

    // ---- cost-descending pair-item map. Bands c=16..9: halves of pair
    // p=c-1 (64 items) plus, when c even, shorts of pair p=c/2-1 (32 items).
    // Tail: shorts p=3..0.
    int p, bh, k0t, k1t, hf = -1;
    if (item < 640) {
      int base = 0, c = 16;
#pragma unroll 1
      for (; c >= 9; --c) {
        int sz = (c & 1) ? 64 : 96;
        if (item < base + sz) break;
        base += sz;
      }
      int off = item - base;
      if (off < 64) {
        p = c - 1; hf = off >> 5; bh = off & 31;
        int hn = p + 1;                       // half point of nk=2p+2
        k0t = hf ? hn : 0; k1t = hf ? 2 * p + 2 : hn;
      } else {
        p = (c >> 1) - 1; bh = off - 64; k0t = 0; k1t = 2 * p + 2;
      }
    } else {
      int off = item - 640;
      p = 3 - (off >> 5); bh = off & 31; k0t = 0; k1t = 2 * p + 2;
    }
    const int b = bh >> 4, h = bh & 15, kh = h >> 2;
    const int qt = 2 * p + qsel;              // this wave's q-tile
    const int qbase = qt * 64 + wv * 16;      // this wave's 16 q-rows

    f16x8 qf[4];
    {
      const f16* qp = QKV + (size_t)(b * Sc + qbase + l16) * QKVS + h * 128 + quad * 8;
#pragma unroll
      for (int c = 0; c < 4; ++c) qf[c] = *(const f16x8*)(qp + c * 32);
    }
    f32x4 ls = {};
    f32x4 o[8] = {};

    // 8-wave staging split: K granule g (g>>2 = row-group, g&3 = k-chunk),
    // V granule g (g>>1 = d-group, g&1 = s-chunk); wave stages g = wave*2+{0,1}.
    auto stageKV = [&](int kt, int buf) {
#pragma unroll
      for (int p2 = 0; p2 < 2; ++p2) {
        const int g = wave * 2 + p2;
        gl_lds16(&QKV[(size_t)(b * Sc + kt * 64 + (g >> 2) * 16 + l16) * QKVS + 2048 + kh * 128 + (g & 3) * 32 + quad * 8],
                 &Kl[buf][g * 512]);
      }
#pragma unroll
      for (int p2 = 0; p2 < 2; ++p2) {
        const int g = wave * 2 + p2;
        gl_lds16(&Vt[(size_t)((b * KHc + kh) * 128 + (g >> 1) * 16 + l16) * Sc + kt * 64 + (g & 1) * 32 + quad * 8],
                 &Vl[buf][g * 512]);
      }
    };

    stageKV(k0t, 0);                          // depth-2 prologue
    stageKV(k0t + 1, 1);                      // k1t-k0t >= 2 for every item

    for (int kt = k0t; kt < k1t; ++kt) {
      const int cur = (kt - k0t) & 1;
      // counted wait: drain own tile-kt DMAs, keep kt+1's 4 in flight
      if (kt + 1 < k1t) { asm volatile("s_waitcnt vmcnt(4)" ::: "memory"); }
      else              { asm volatile("s_waitcnt vmcnt(0)" ::: "memory"); }
      __builtin_amdgcn_sched_barrier(0);
      __builtin_amdgcn_s_barrier();           // all granules for tile kt landed
      __builtin_amdgcn_sched_barrier(0);

      if (kt <= qt) {                         // wave-uniform causal skip
        // ---- scores for all 4 16-col groups
        __builtin_amdgcn_s_setprio(1);
        f32x4 s4[4] = {};
#pragma unroll
        for (int kc = 0; kc < 2; ++kc)
#pragma unroll
          for (int c = 0; c < 4; ++c) {
            f16x8 ka = *(const f16x8*)&Kl[cur][(((kc * 2 + 0) * 4 + c) * 4 + quad) * 128 + l16 * 8];
            f16x8 kb = *(const f16x8*)&Kl[cur][(((kc * 2 + 1) * 4 + c) * 4 + quad) * 128 + l16 * 8];
            s4[kc * 2 + 0] = __builtin_amdgcn_mfma_f32_16x16x32_f16(qf[c], ka, s4[kc * 2 + 0], 0, 0, 0);
            s4[kc * 2 + 1] = __builtin_amdgcn_mfma_f32_16x16x32_f16(qf[c], kb, s4[kc * 2 + 1], 0, 0, 0);
          }
        __builtin_amdgcn_s_setprio(0);

        // ---- softmax, fixed shift M0c (exp2 domain); mask only on diag tile
        const bool diag = (kt == qt);
        const int cb = kt * 64 + l16;
        const int wb  = wave * 512 + (l16 & 7);
        const int rhi = l16 >> 3;
        float e2[4], e3[4];
#pragma unroll
        for (int r = 0; r < 4; ++r) {
          float v0 = fmaf(s4[0][r], SCALE2c, -M0c);
          float v1 = fmaf(s4[1][r], SCALE2c, -M0c);
          float v2 = fmaf(s4[2][r], SCALE2c, -M0c);
          float v3 = fmaf(s4[3][r], SCALE2c, -M0c);
          if (diag) {
            const int qrow = qbase + quad * 4 + r;
            if (cb      > qrow) v0 = -1e30f;
            if (cb + 16 > qrow) v1 = -1e30f;
            if (cb + 32 > qrow) v2 = -1e30f;
            if (cb + 48 > qrow) v3 = -1e30f;
          }
          float p0 = exp2f(v0), p1 = exp2f(v1);
          e2[r] = exp2f(v2); e3[r] = exp2f(v3);
          const int rowoff = (quad * 4 + r) * 8;
          Ps[wb + (rhi + 0) * 128 + rowoff] = (f16)p0;
          Ps[wb + (rhi + 2) * 128 + rowoff] = (f16)p1;
        }

        // ---- PV chunk kc=0 (cols 0..31) + row-sum MFMA (Ps wave-local)
        {
          f16x8 pf = *(const f16x8*)&Ps[wave * 512 + quad * 128 + l16 * 8];
          __builtin_amdgcn_s_setprio(1);
          ls = __builtin_amdgcn_mfma_f32_16x16x32_f16(pf, ones_f, ls, 0, 0, 0);
#pragma unroll
          for (int dt = 0; dt < 8; ++dt) {
            f16x8 vf = *(const f16x8*)&Vl[cur][((dt * 2 + 0) * 4 + quad) * 128 + l16 * 8];
            o[dt] = __builtin_amdgcn_mfma_f32_16x16x32_f16(pf, vf, o[dt], 0, 0, 0);
          }
          __builtin_amdgcn_s_setprio(0);
        }
        // ---- PV chunk kc=1 (cols 32..63); wave-local DS in-order -> WAR-safe
#pragma unroll
        for (int r = 0; r < 4; ++r) {
          const int rowoff = (quad * 4 + r) * 8;
          Ps[wb + (rhi + 0) * 128 + rowoff] = (f16)e2[r];
          Ps[wb + (rhi + 2) * 128 + rowoff] = (f16)e3[r];
        }
        {
          f16x8 pf = *(const f16x8*)&Ps[wave * 512 + quad * 128 + l16 * 8];
          __builtin_amdgcn_s_setprio(1);
          ls = __builtin_amdgcn_mfma_f32_16x16x32_f16(pf, ones_f, ls, 0, 0, 0);
#pragma unroll
          for (int dt = 0; dt < 8; ++dt) {
            f16x8 vf = *(const f16x8*)&Vl[cur][((dt * 2 + 1) * 4 + quad) * 128 + l16 * 8];
            o[dt] = __builtin_amdgcn_mfma_f32_16x16x32_f16(pf, vf, o[dt], 0, 0, 0);
          }
          __builtin_amdgcn_s_setprio(0);
        }
      }

      // end barrier: all waves' reads of buf[cur] retired -> WAR-safe restage
      __builtin_amdgcn_sched_barrier(0);
      __builtin_amdgcn_s_barrier();
      __builtin_amdgcn_sched_barrier(0);
      if (kt + 2 < k1t) stageKV(kt + 2, cur);   // tile kt+2 uses buf[cur]
    }

    // ---- epilogue: l lives in lanes l16==0 (C col 0); broadcast within quad
    float inv[4], lrow[4];
#pragma unroll
    for (int r = 0; r < 4; ++r) {
      lrow[r] = __shfl(ls[r], lane & 48);
      inv[r] = 1.0f / lrow[r];
    }
    const int rl = wv * 16 + quad * 4;
    if (hf < 0) {
#pragma unroll
      for (int dt = 0; dt < 8; ++dt)
#pragma unroll
        for (int r = 0; r < 4; ++r)
          Ob[(size_t)(b * Sc + qbase + quad * 4 + r) * HDc + h * 128 + dt * 16 + l16] =
              (f16)(o[dt][r] * inv[r]);
    } else {
      const int tile = (qt - 16) * 32 + bh;   // qt = 2p+qsel in 16..31 for p>=8
      f16* op = Opart + ((size_t)tile * 2 + hf) * (64 * 128);
#pragma unroll
      for (int dt = 0; dt < 8; ++dt)
#pragma unroll
        for (int r = 0; r < 4; ++r)
          op[(rl + r) * 128 + dt * 16 + l16] = (f16)(o[dt][r] * inv[r]);
      if (l16 == 0) {
#pragma unroll
        for (int r = 0; r < 4; ++r) {
          float2 ml; ml.x = M0c; ml.y = lrow[r];
          ML[((size_t)tile * 2 + hf) * 64 + rl + r] = ml;
        }
      }
    }
  }
}

// ---------------------------------------------------------------- merge split-K halves
__global__ __launch_bounds__(256) void attn_merge(const f16* __restrict__ Opart,
                                                  const float2* __restrict__ ML,
                                                  f16* __restrict__ Ob) {
  const int tile = blockIdx.x;
  const int qt = 16 + (tile >> 5), bh = tile & 31;
  const int b = bh >> 4, h = bh & 15;
  const int tid = threadIdx.x;
  const int row = tid >> 2, c0 = (tid & 3) * 32;
  float2 ml1 = ML[(size_t)tile * 2 * 64 + row];
  float2 ml2 = ML[((size_t)tile * 2 + 1) * 64 + row];
  float m = fmaxf(ml1.x, ml2.x);
  float w1 = ml1.y * exp2f(ml1.x - m);
  float w2 = ml2.y * exp2f(ml2.x - m);
  float rinv = 1.0f / (w1 + w2);
  float a1 = w1 * rinv, a2 = w2 * rinv;
  const f16* o1 = Opart + (size_t)tile * 2 * (64 * 128) + row * 128 + c0;
  const f16* o2 = o1 + 64 * 128;
  f16* out = Ob + (size_t)(b * Sc + qt * 64 + row) * HDc + h * 128 + c0;
#pragma unroll
  for (int j = 0; j < 4; ++j) {
    f16x8 x1 = *(const f16x8*)(o1 + j * 8);
    f16x8 x2 = *(const f16x8*)(o2 + j * 8);
    f16x8 y;
#pragma unroll
    for (int i = 0; i < 8; ++i) y[i] = (f16)(a1 * (float)x1[i] + a2 * (float)x2[i]);
    *(f16x8*)(out + j * 8) = y;
  }
}

// ---------------------------------------------------------------- launch
extern "C" void kernel_launch(void* const* d_in, const int* in_sizes, int n_in,
                              void* d_out, int out_size, void* d_ws, size_t ws_size,
                              hipStream_t stream) {
  (void)in_sizes; (void)n_in; (void)out_size; (void)ws_size;
  const float* hs   = (const float*)d_in[0];
  const float* cosb = (const float*)d_in[1];
  const float* sinb = (const float*)d_in[2];
  // d_in[3] = attention_mask: pure causal, in-kernel.
  const float* wq = (const float*)d_in[4];
  const float* wk = (const float*)d_in[5];
  const float* wv = (const float*)d_in[6];
  const float* wo = (const float*)d_in[7];
  float* out = (float*)d_out;

  char* ws = (char*)d_ws;
  int*  ctr = (int*)ws;
  size_t off = 256;
  auto alloc = [&](size_t bytes) { char* p = ws + off; off += (bytes + 255) & ~(size_t)255; return p; };
  f16*  hsF   = (f16*)alloc((size_t)Bc * Sc * HIDc * 2);      // 16.8 MB (reused as attn out)
  f16*  woT   = (f16*)alloc((size_t)HIDc * HDc * 2);          //  8.4 MB
  f16*  QKVf  = (f16*)alloc((size_t)Bc * Sc * QKVS * 2);      // 25.2 MB
  f16*  Vt_g  = (f16*)alloc((size_t)Bc * KHc * Dc * Sc * 2);  //  4.2 MB
  f16*  wqkvT = (f16*)alloc((size_t)QKVS * HIDc * 2);         // 12.6 MB (dead after QKV GEMM)
  // Opart aliases wqkvT (16.8 MB needs 12.6 + 4.2 fresh tail)
  f16*  Opart = wqkvT;
  {
    size_t opart_bytes = (size_t)512 * 2 * 64 * 128 * 2;      // 16.8 MB
    size_t wqkvT_bytes = (size_t)QKVS * HIDc * 2;
    if (opart_bytes > wqkvT_bytes) off += opart_bytes - wqkvT_bytes;
  }
  float2* ML = (float2*)alloc((size_t)512 * 2 * 64 * sizeof(float2));  // 0.5 MB
  f16*  attnF = hsF;   // hsF dead after QKV GEMM

  conv_hs<<<8192, 256, 0, stream>>>(hs, hsF, ctr);
  trw_all<<<dim3(32, 32, 4), 256, 0, stream>>>(wq, wk, wv, wo, wqkvT, woT);

  // QKV GEMM: C(4096,3072) f16 stride QKVS; 256x192 tiles -> grid 16x16 = 256 blocks (1/CU)
  gemm4p<3, 1><<<dim3(16, 16), 512, 0, stream>>>(hsF, wqkvT, QKVf, 2048, QKVS);

  rope8<<<2560, 256, 0, stream>>>(QKVf, cosb, sinb);
  v_tr<<<dim3(32, 2, 8), 256, 0, stream>>>(QKVf, Vt_g);

  attn_v8<<<512, 512, 0, stream>>>(QKVf, Vt_g, attnF, Opart, ML, ctr);
  attn_merge<<<512, 256, 0, stream>>>(Opart, ML, attnF);

  // out-proj GEMM: C(4096,2048) f32; 256x128 tiles -> grid 16x16 = 256 blocks (1/CU)
  gemm4p<2, 0><<<dim3(16, 16), 512, 0, stream>>>(attnF, woT, out, 2048, 2048);
}